// Round 4
// baseline (219.454 us; speedup 1.0000x reference)
//
#include <hip/hip_runtime.h>
#include <hip/hip_bf16.h>
#include <math.h>

typedef __bf16 bf16v8 __attribute__((ext_vector_type(8)));
typedef float  f32x4  __attribute__((ext_vector_type(4)));

__device__ __forceinline__ void gload_lds16(const void* g, void* l) {
    __builtin_amdgcn_global_load_lds(
        (const __attribute__((address_space(1))) unsigned int*)g,
        (__attribute__((address_space(3))) unsigned int*)l, 16, 0, 0);
}

// convert 8 fp32 -> 8 bf16, store one b128
__device__ __forceinline__ void cvt_store8(void* dst, float4 a, float4 b) {
    bf16v8 v;
    v[0] = (__bf16)a.x; v[1] = (__bf16)a.y; v[2] = (__bf16)a.z; v[3] = (__bf16)a.w;
    v[4] = (__bf16)b.x; v[5] = (__bf16)b.y; v[6] = (__bf16)b.z; v[7] = (__bf16)b.w;
    *(bf16v8*)dst = v;
}

// ---------------------------------------------------------------------------
// Kernel 1: W_img (2048x512 f32, k-major) -> Wt (512x2048 bf16, a-major)
// ---------------------------------------------------------------------------
__global__ __launch_bounds__(256) void wt_k(const float* __restrict__ W,
                                            unsigned short* __restrict__ Wt)
{
    __shared__ float tile[64][65];
    const int k0 = blockIdx.x * 64;
    const int a0 = blockIdx.y * 64;
    const int t = threadIdx.x;
    const int c = t & 63, rbase = t >> 6;
#pragma unroll
    for (int i = 0; i < 16; ++i) {
        int kr = rbase + i * 4;
        tile[kr][c] = W[(k0 + kr) * 512 + a0 + c];
    }
    __syncthreads();
#pragma unroll
    for (int i = 0; i < 16; ++i) {
        int ar = rbase + i * 4;
        Wt[(a0 + ar) * 2048 + k0 + c] =
            __builtin_bit_cast(unsigned short, (__bf16)tile[c][ar]);
    }
}

// ---------------------------------------------------------------------------
// Kernel 2: hb[b][a] = hidden[b]@W_hid[:,a] + b_hid[a] + b_img[a];
//           beta[b] = sigmoid(hidden[b]@w_beta + b_beta)
// ---------------------------------------------------------------------------
__global__ __launch_bounds__(256) void hid_k(
    const float* __restrict__ hidden, const float* __restrict__ W_hid,
    const float* __restrict__ b_hid,  const float* __restrict__ b_img,
    const float* __restrict__ w_beta, const float* __restrict__ b_beta,
    float* __restrict__ hb, float* __restrict__ betap)
{
    const int b = blockIdx.x, t = threadIdx.x;
    __shared__ float hs[512];
    __shared__ float red[4];
    hs[t]       = hidden[b * 512 + t];
    hs[t + 256] = hidden[b * 512 + 256 + t];
    __syncthreads();
    float a0 = 0.f, a1 = 0.f;
#pragma unroll 4
    for (int h = 0; h < 512; ++h) {
        float hv = hs[h];
        a0 = fmaf(hv, W_hid[h * 512 + t], a0);
        a1 = fmaf(hv, W_hid[h * 512 + 256 + t], a1);
    }
    hb[b * 512 + t]       = a0 + b_hid[t]       + b_img[t];
    hb[b * 512 + 256 + t] = a1 + b_hid[256 + t] + b_img[256 + t];

    float x = hs[t] * w_beta[t] + hs[t + 256] * w_beta[t + 256];
#pragma unroll
    for (int k = 32; k >= 1; k >>= 1) x += __shfl_xor(x, k, 64);
    const int lane = t & 63, wid = t >> 6;
    if (lane == 0) red[wid] = x;
    __syncthreads();
    if (t == 0) {
        float s = red[0] + red[1] + red[2] + red[3] + b_beta[0];
        betap[b] = 1.f / (1.f + __expf(-s));
    }
}

// ---------------------------------------------------------------------------
// Kernel 3: fused scores GEMM. BM=64, BN=128, BK=32, grid 1568 (6.1/CU).
//   A: fp32 global -> regs (depth-2) -> cvt bf16 -> LDS [64 rows][80B].
//   B: global_load_lds bf16 [128 cols][64B], XOR swizzle via source addr.
//   Main loop: counted barrier (vmcnt(2)) keeps A-prefetch flying across
//   the barrier; prologue + last 4 bodies peeled with full __syncthreads.
// ---------------------------------------------------------------------------
#define NKIT 64   // 2048 / 32

__global__ __launch_bounds__(256, 5) void scores_gemm(
    const float* __restrict__ img,            // [25088][2048] f32
    const unsigned short* __restrict__ Wt,    // [512][2048] bf16 bits
    const float* __restrict__ hb,             // [128][512]
    const float* __restrict__ w_att,          // [512]
    float* __restrict__ partials)             // [4][25088]
{
    __shared__ __align__(16) char smem[26624];
    char* A0 = smem;            // 64*80 = 5120
    char* A1 = smem + 5120;
    char* B0 = smem + 10240;    // 128*64 = 8192
    char* B1 = smem + 18432;

    const int tid  = threadIdx.x;
    const int lane = tid & 63;
    const int wid  = tid >> 6;
    const int wm   = wid >> 1;   // 0..1 (32-row half)
    const int wn   = wid & 1;    // 0..1 (64-col half)

    // XCD-bijective swizzle: 1568 = 8*196
    const int id = blockIdx.x;
    const int wg = (id & 7) * 196 + (id >> 3);
    const int cb    = wg & 3;
    const int mtile = wg >> 2;   // 0..391
    const int r0 = mtile * 64;
    const int a0 = cb * 128;

    // A staging: thread -> row = tid>>2 (0..63), quarter q = tid&3 (8 elems)
    const int arow = tid >> 2;
    const int aq   = tid & 3;
    const float* gA = img + (size_t)(r0 + arow) * 2048 + aq * 8;
    const int aW = arow * 80 + aq * 16;

    // B staging: LDS pos p = r*4096 + tid*16; col = r*64 + (tid>>2)
    const int bswz = ((tid & 3) ^ ((tid >> 3) & 3)) * 8;
    const unsigned short* gB0 = Wt + (size_t)(a0 + (tid >> 2)) * 2048 + bswz;
    const unsigned short* gB1 = Wt + (size_t)(a0 + 64 + (tid >> 2)) * 2048 + bswz;
    const int bW0 = tid * 16;
    const int bW1 = 4096 + tid * 16;

    const int g  = lane >> 4;
    const int fl = lane & 15;
    const int bro = (g ^ ((fl >> 1) & 3)) << 4;   // B read XOR offset

    f32x4 acc[2][4] = {};
    float4 rA0[2], rA1[2];

    // ---------------- prologue (full-drain barriers, safe) ----------------
    rA0[0] = *(const float4*)(gA);
    rA0[1] = *(const float4*)(gA + 4);
    gload_lds16(gB0, B0 + bW0);
    gload_lds16(gB1, B0 + bW1);
    __builtin_amdgcn_sched_barrier(0);
    cvt_store8(A0 + aW, rA0[0], rA0[1]);          // tile 0 -> A0
    rA0[0] = *(const float4*)(gA + 32);           // data(1)
    rA0[1] = *(const float4*)(gA + 36);
    rA1[0] = *(const float4*)(gA + 64);           // data(2)
    rA1[1] = *(const float4*)(gA + 68);
    __syncthreads();                               // full drain: all staged

#define BODY(K, CA, CB, NA, NB, RC, STAGE, RELOAD, FULLBAR) do {            \
    bf16v8 av0, av1, bv0, bv1, bv2, bv3;                                     \
    {                                                                        \
        int row0 = wm * 32 + fl;                                             \
        av0 = *(const bf16v8*)(CA + row0 * 80 + g * 16);                     \
        av1 = *(const bf16v8*)(CA + (row0 + 16) * 80 + g * 16);              \
        int c0 = wn * 64 + fl;                                               \
        bv0 = *(const bf16v8*)(CB + c0 * 64 + bro);                          \
        bv1 = *(const bf16v8*)(CB + (c0 + 16) * 64 + bro);                   \
        bv2 = *(const bf16v8*)(CB + (c0 + 32) * 64 + bro);                   \
        bv3 = *(const bf16v8*)(CB + (c0 + 48) * 64 + bro);                   \
    }                                                                        \
    if (STAGE) {                                                             \
        gload_lds16(gB0 + (K + 1) * 32, NB + bW0);                           \
        gload_lds16(gB1 + (K + 1) * 32, NB + bW1);                           \
    }                                                                        \
    __builtin_amdgcn_sched_barrier(0);                                       \
    if (STAGE) cvt_store8(NA + aW, RC[0], RC[1]);                            \
    if (RELOAD) {                                                            \
        RC[0] = *(const float4*)(gA + (K + 3) * 32);                         \
        RC[1] = *(const float4*)(gA + (K + 3) * 32 + 4);                     \
    }                                                                        \
    __builtin_amdgcn_sched_barrier(0);                                       \
    acc[0][0] = __builtin_amdgcn_mfma_f32_16x16x32_bf16(av0, bv0, acc[0][0], 0, 0, 0); \
    acc[0][1] = __builtin_amdgcn_mfma_f32_16x16x32_bf16(av0, bv1, acc[0][1], 0, 0, 0); \
    acc[0][2] = __builtin_amdgcn_mfma_f32_16x16x32_bf16(av0, bv2, acc[0][2], 0, 0, 0); \
    acc[0][3] = __builtin_amdgcn_mfma_f32_16x16x32_bf16(av0, bv3, acc[0][3], 0, 0, 0); \
    acc[1][0] = __builtin_amdgcn_mfma_f32_16x16x32_bf16(av1, bv0, acc[1][0], 0, 0, 0); \
    acc[1][1] = __builtin_amdgcn_mfma_f32_16x16x32_bf16(av1, bv1, acc[1][1], 0, 0, 0); \
    acc[1][2] = __builtin_amdgcn_mfma_f32_16x16x32_bf16(av1, bv2, acc[1][2], 0, 0, 0); \
    acc[1][3] = __builtin_amdgcn_mfma_f32_16x16x32_bf16(av1, bv3, acc[1][3], 0, 0, 0); \
    if (FULLBAR) {                                                           \
        __syncthreads();                                                     \
    } else {                                                                 \
        __builtin_amdgcn_sched_barrier(0);                                   \
        asm volatile("s_waitcnt vmcnt(2) lgkmcnt(0)" ::: "memory");          \
        __builtin_amdgcn_s_barrier();                                        \
        __builtin_amdgcn_sched_barrier(0);                                   \
    }                                                                        \
} while (0)

    // ---------------- main loop: bodies 0..59, counted barriers ----------
    for (int t = 0; t < 60; t += 2) {
        BODY(t,     A0, B0, A1, B1, rA0, true, true, false);
        BODY(t + 1, A1, B1, A0, B0, rA1, true, true, false);
    }
    // ---------------- tail: bodies 60..63, full barriers ------------------
    BODY(60, A0, B0, A1, B1, rA0, true,  true,  true);   // reload rA0<-data63
    BODY(61, A1, B1, A0, B0, rA1, true,  false, true);
    BODY(62, A0, B0, A1, B1, rA0, true,  false, true);
    BODY(63, A1, B1, A0, B0, rA1, false, false, true);
#undef BODY

    // ---------------- epilogue: relu(acc + hb) * w_att, col-reduce --------
    float* red = (float*)smem;   // [2][64]
    const int l4 = lane >> 4;

    float w4[4];
#pragma unroll
    for (int fn = 0; fn < 4; ++fn) w4[fn] = w_att[a0 + wn * 64 + fn * 16 + fl];

#pragma unroll
    for (int fm = 0; fm < 2; ++fm) {
#pragma unroll
        for (int rg = 0; rg < 4; ++rg) {
            int row = wm * 32 + fm * 16 + l4 * 4 + rg;
            int grow = r0 + row;
            int bb = grow / 196;
            const float* hbrow = hb + bb * 512 + a0 + wn * 64;
            float s = 0.f;
#pragma unroll
            for (int fn = 0; fn < 4; ++fn) {
                float v = acc[fm][fn][rg] + hbrow[fn * 16 + fl];
                v = fmaxf(v, 0.f);
                s = fmaf(v, w4[fn], s);
            }
#pragma unroll
            for (int m = 1; m < 16; m <<= 1) s += __shfl_xor(s, m, 64);
            if (fl == 0) red[wn * 64 + row] = s;
        }
    }
    __syncthreads();
    if (tid < 64) {
        partials[cb * 25088 + r0 + tid] = red[tid] + red[64 + tid];
    }
}

// ---------------------------------------------------------------------------
// Kernel 4: softmax over N=196 per batch.
// ---------------------------------------------------------------------------
__global__ __launch_bounds__(256) void softmax_k(
    const float* __restrict__ partials, const float* __restrict__ betap,
    const float* __restrict__ b_att,
    float* __restrict__ out_w, float* __restrict__ wbeta)
{
    const int b = blockIdx.x;
    const int t = threadIdx.x;
    const int lane = t & 63, wid = t >> 6;
    __shared__ float red[4];

    float scv = 0.f, sc = -1e30f;
    if (t < 196) {
        int r = b * 196 + t;
        scv = partials[r] + partials[25088 + r] + partials[2 * 25088 + r] +
              partials[3 * 25088 + r] + b_att[0];
        sc = scv;
    }
    float m = sc;
#pragma unroll
    for (int k = 32; k >= 1; k >>= 1) m = fmaxf(m, __shfl_xor(m, k, 64));
    if (lane == 0) red[wid] = m;
    __syncthreads();
    m = fmaxf(fmaxf(red[0], red[1]), fmaxf(red[2], red[3]));

    float e = (t < 196) ? __expf(scv - m) : 0.f;
    float ssum = e;
#pragma unroll
    for (int k = 32; k >= 1; k >>= 1) ssum += __shfl_xor(ssum, k, 64);
    __syncthreads();
    if (lane == 0) red[wid] = ssum;
    __syncthreads();
    float denom = red[0] + red[1] + red[2] + red[3];

    if (t < 196) {
        float w = e / denom;
        out_w[b * 196 + t] = w;
        wbeta[b * 196 + t] = w * betap[b];
    }
}

// ---------------------------------------------------------------------------
// Kernel 5: context[b][c] = sum_n wbeta[b][n] * img[b][n][c]
// ---------------------------------------------------------------------------
__global__ __launch_bounds__(256) void ctx_k(
    const float* __restrict__ img, const float* __restrict__ wbeta,
    float* __restrict__ out)
{
    const int b = blockIdx.y;
    const int c0 = blockIdx.x * 512 + threadIdx.x * 2;
    __shared__ float w[200];
    if (threadIdx.x < 196) w[threadIdx.x] = wbeta[b * 196 + threadIdx.x];
    __syncthreads();
    const float* base = img + (size_t)b * 196 * 2048 + c0;
    float acx = 0.f, acy = 0.f;
#pragma unroll 4
    for (int n = 0; n < 196; ++n) {
        float2 v = *(const float2*)(base + (size_t)n * 2048);
        float wn = w[n];
        acx = fmaf(wn, v.x, acx);
        acy = fmaf(wn, v.y, acy);
    }
    float2 r; r.x = acx; r.y = acy;
    *(float2*)(out + b * 2048 + c0) = r;
}

// ---------------------------------------------------------------------------
extern "C" void kernel_launch(void* const* d_in, const int* in_sizes, int n_in,
                              void* d_out, int out_size, void* d_ws, size_t ws_size,
                              hipStream_t stream)
{
    const float* img    = (const float*)d_in[0];
    const float* hidden = (const float*)d_in[1];
    const float* W_img  = (const float*)d_in[2];
    const float* b_img  = (const float*)d_in[3];
    const float* W_hid  = (const float*)d_in[4];
    const float* b_hid  = (const float*)d_in[5];
    const float* w_att  = (const float*)d_in[6];
    const float* b_att  = (const float*)d_in[7];
    const float* w_beta = (const float*)d_in[8];
    const float* b_beta = (const float*)d_in[9];

    char* ws = (char*)d_ws;
    unsigned short* Wt = (unsigned short*)ws;            // [512][2048] bf16: 2 MB
    float* hbp   = (float*)(ws + 2097152);               // [128][512]
    float* betap = (float*)(ws + 2359296);               // [128]
    float* parts = (float*)(ws + 2359808);               // [4][25088]
    float* wbeta = (float*)(ws + 2761216);               // [128][196]

    float* out_ctx = (float*)d_out;                      // [128][2048]
    float* out_w   = out_ctx + 128 * 2048;               // [128][196]

    wt_k<<<dim3(32, 8), 256, 0, stream>>>(W_img, Wt);
    hid_k<<<128, 256, 0, stream>>>(hidden, W_hid, b_hid, b_img, w_beta, b_beta,
                                   hbp, betap);
    scores_gemm<<<1568, 256, 0, stream>>>(img, Wt, hbp, w_att, parts);
    softmax_k<<<128, 256, 0, stream>>>(parts, betap, b_att, out_w, wbeta);
    ctx_k<<<dim3(4, 128), 256, 0, stream>>>(img, wbeta, out_ctx);
}

// Round 5
// 180.066 us; speedup vs baseline: 1.2187x; 1.2187x over previous
//
#include <hip/hip_runtime.h>
#include <hip/hip_bf16.h>
#include <math.h>

typedef __bf16 bf16v8 __attribute__((ext_vector_type(8)));
typedef float  f32x4  __attribute__((ext_vector_type(4)));

__device__ __forceinline__ void gload_lds16(const void* g, void* l) {
    __builtin_amdgcn_global_load_lds(
        (const __attribute__((address_space(1))) unsigned int*)g,
        (__attribute__((address_space(3))) unsigned int*)l, 16, 0, 0);
}

// convert 8 fp32 -> 8 bf16, store one b128
__device__ __forceinline__ void cvt_store8(void* dst, float4 a, float4 b) {
    bf16v8 v;
    v[0] = (__bf16)a.x; v[1] = (__bf16)a.y; v[2] = (__bf16)a.z; v[3] = (__bf16)a.w;
    v[4] = (__bf16)b.x; v[5] = (__bf16)b.y; v[6] = (__bf16)b.z; v[7] = (__bf16)b.w;
    *(bf16v8*)dst = v;
}

// ---------------------------------------------------------------------------
// Kernel 1: W_img (2048x512 f32, k-major) -> Wt (512x2048 bf16, a-major)
// ---------------------------------------------------------------------------
__global__ __launch_bounds__(256) void wt_k(const float* __restrict__ W,
                                            unsigned short* __restrict__ Wt)
{
    __shared__ float tile[64][65];
    const int k0 = blockIdx.x * 64;
    const int a0 = blockIdx.y * 64;
    const int t = threadIdx.x;
    const int c = t & 63, rbase = t >> 6;
#pragma unroll
    for (int i = 0; i < 16; ++i) {
        int kr = rbase + i * 4;
        tile[kr][c] = W[(k0 + kr) * 512 + a0 + c];
    }
    __syncthreads();
#pragma unroll
    for (int i = 0; i < 16; ++i) {
        int ar = rbase + i * 4;
        Wt[(a0 + ar) * 2048 + k0 + c] =
            __builtin_bit_cast(unsigned short, (__bf16)tile[c][ar]);
    }
}

// ---------------------------------------------------------------------------
// Kernel 2: hb[b][a] = hidden[b]@W_hid[:,a] + b_hid[a] + b_img[a];
//           beta[b] = sigmoid(hidden[b]@w_beta + b_beta)
// ---------------------------------------------------------------------------
__global__ __launch_bounds__(256) void hid_k(
    const float* __restrict__ hidden, const float* __restrict__ W_hid,
    const float* __restrict__ b_hid,  const float* __restrict__ b_img,
    const float* __restrict__ w_beta, const float* __restrict__ b_beta,
    float* __restrict__ hb, float* __restrict__ betap)
{
    const int b = blockIdx.x, t = threadIdx.x;
    __shared__ float hs[512];
    __shared__ float red[4];
    hs[t]       = hidden[b * 512 + t];
    hs[t + 256] = hidden[b * 512 + 256 + t];
    __syncthreads();
    float a0 = 0.f, a1 = 0.f;
#pragma unroll 4
    for (int h = 0; h < 512; ++h) {
        float hv = hs[h];
        a0 = fmaf(hv, W_hid[h * 512 + t], a0);
        a1 = fmaf(hv, W_hid[h * 512 + 256 + t], a1);
    }
    hb[b * 512 + t]       = a0 + b_hid[t]       + b_img[t];
    hb[b * 512 + 256 + t] = a1 + b_hid[256 + t] + b_img[256 + t];

    float x = hs[t] * w_beta[t] + hs[t + 256] * w_beta[t + 256];
#pragma unroll
    for (int k = 32; k >= 1; k >>= 1) x += __shfl_xor(x, k, 64);
    const int lane = t & 63, wid = t >> 6;
    if (lane == 0) red[wid] = x;
    __syncthreads();
    if (t == 0) {
        float s = red[0] + red[1] + red[2] + red[3] + b_beta[0];
        betap[b] = 1.f / (1.f + __expf(-s));
    }
}

// ---------------------------------------------------------------------------
// Kernel 3: fused scores GEMM. BM=64, BN=128, BK=32, grid 1568 (6.1/CU).
//   A: fp32 global -> regs (depth-2) -> cvt bf16 -> LDS [64 rows][80B].
//   B: global_load_lds bf16 [128 cols][64B], XOR swizzle via source addr.
//   Main loop: counted barrier (vmcnt(2)) keeps A-prefetch flying across
//   the barrier; prologue + last 4 bodies peeled with full __syncthreads.
//   launch_bounds (256,4): VGPR budget 128 -- no spills (r4's (256,5)
//   forced 48 VGPR and spilled 30 MB to scratch).
// ---------------------------------------------------------------------------
#define NKIT 64   // 2048 / 32

__global__ __launch_bounds__(256, 4) void scores_gemm(
    const float* __restrict__ img,            // [25088][2048] f32
    const unsigned short* __restrict__ Wt,    // [512][2048] bf16 bits
    const float* __restrict__ hb,             // [128][512]
    const float* __restrict__ w_att,          // [512]
    float* __restrict__ partials)             // [4][25088]
{
    __shared__ __align__(16) char smem[26624];
    char* A0 = smem;            // 64*80 = 5120
    char* A1 = smem + 5120;
    char* B0 = smem + 10240;    // 128*64 = 8192
    char* B1 = smem + 18432;

    const int tid  = threadIdx.x;
    const int lane = tid & 63;
    const int wid  = tid >> 6;
    const int wm   = wid >> 1;   // 0..1 (32-row half)
    const int wn   = wid & 1;    // 0..1 (64-col half)

    // XCD-bijective swizzle: 1568 = 8*196
    const int id = blockIdx.x;
    const int wg = (id & 7) * 196 + (id >> 3);
    const int cb    = wg & 3;
    const int mtile = wg >> 2;   // 0..391
    const int r0 = mtile * 64;
    const int a0 = cb * 128;

    // A staging: thread -> row = tid>>2 (0..63), quarter q = tid&3 (8 elems)
    const int arow = tid >> 2;
    const int aq   = tid & 3;
    const float* gA = img + (size_t)(r0 + arow) * 2048 + aq * 8;
    const int aW = arow * 80 + aq * 16;

    // B staging: LDS pos p = r*4096 + tid*16; col = r*64 + (tid>>2)
    const int bswz = ((tid & 3) ^ ((tid >> 3) & 3)) * 8;
    const unsigned short* gB0 = Wt + (size_t)(a0 + (tid >> 2)) * 2048 + bswz;
    const unsigned short* gB1 = Wt + (size_t)(a0 + 64 + (tid >> 2)) * 2048 + bswz;
    const int bW0 = tid * 16;
    const int bW1 = 4096 + tid * 16;

    const int g  = lane >> 4;
    const int fl = lane & 15;
    const int bro = (g ^ ((fl >> 1) & 3)) << 4;   // B read XOR offset

    f32x4 acc[2][4] = {};
    float4 rA0[2], rA1[2];

    // ---------------- prologue (full-drain barriers, safe) ----------------
    rA0[0] = *(const float4*)(gA);
    rA0[1] = *(const float4*)(gA + 4);
    gload_lds16(gB0, B0 + bW0);
    gload_lds16(gB1, B0 + bW1);
    __builtin_amdgcn_sched_barrier(0);
    cvt_store8(A0 + aW, rA0[0], rA0[1]);          // tile 0 -> A0
    rA0[0] = *(const float4*)(gA + 32);           // data(1)
    rA0[1] = *(const float4*)(gA + 36);
    rA1[0] = *(const float4*)(gA + 64);           // data(2)
    rA1[1] = *(const float4*)(gA + 68);
    __syncthreads();                               // full drain: all staged

#define BODY(K, CA, CB, NA, NB, RC, STAGE, RELOAD, FULLBAR) do {            \
    bf16v8 av0, av1, bv0, bv1, bv2, bv3;                                     \
    {                                                                        \
        int row0 = wm * 32 + fl;                                             \
        av0 = *(const bf16v8*)(CA + row0 * 80 + g * 16);                     \
        av1 = *(const bf16v8*)(CA + (row0 + 16) * 80 + g * 16);              \
        int c0 = wn * 64 + fl;                                               \
        bv0 = *(const bf16v8*)(CB + c0 * 64 + bro);                          \
        bv1 = *(const bf16v8*)(CB + (c0 + 16) * 64 + bro);                   \
        bv2 = *(const bf16v8*)(CB + (c0 + 32) * 64 + bro);                   \
        bv3 = *(const bf16v8*)(CB + (c0 + 48) * 64 + bro);                   \
    }                                                                        \
    if (STAGE) {                                                             \
        gload_lds16(gB0 + (K + 1) * 32, NB + bW0);                           \
        gload_lds16(gB1 + (K + 1) * 32, NB + bW1);                           \
    }                                                                        \
    __builtin_amdgcn_sched_barrier(0);                                       \
    if (STAGE) cvt_store8(NA + aW, RC[0], RC[1]);                            \
    if (RELOAD) {                                                            \
        RC[0] = *(const float4*)(gA + (K + 3) * 32);                         \
        RC[1] = *(const float4*)(gA + (K + 3) * 32 + 4);                     \
    }                                                                        \
    __builtin_amdgcn_sched_barrier(0);                                       \
    acc[0][0] = __builtin_amdgcn_mfma_f32_16x16x32_bf16(av0, bv0, acc[0][0], 0, 0, 0); \
    acc[0][1] = __builtin_amdgcn_mfma_f32_16x16x32_bf16(av0, bv1, acc[0][1], 0, 0, 0); \
    acc[0][2] = __builtin_amdgcn_mfma_f32_16x16x32_bf16(av0, bv2, acc[0][2], 0, 0, 0); \
    acc[0][3] = __builtin_amdgcn_mfma_f32_16x16x32_bf16(av0, bv3, acc[0][3], 0, 0, 0); \
    acc[1][0] = __builtin_amdgcn_mfma_f32_16x16x32_bf16(av1, bv0, acc[1][0], 0, 0, 0); \
    acc[1][1] = __builtin_amdgcn_mfma_f32_16x16x32_bf16(av1, bv1, acc[1][1], 0, 0, 0); \
    acc[1][2] = __builtin_amdgcn_mfma_f32_16x16x32_bf16(av1, bv2, acc[1][2], 0, 0, 0); \
    acc[1][3] = __builtin_amdgcn_mfma_f32_16x16x32_bf16(av1, bv3, acc[1][3], 0, 0, 0); \
    if (FULLBAR) {                                                           \
        __syncthreads();                                                     \
    } else {                                                                 \
        __builtin_amdgcn_sched_barrier(0);                                   \
        asm volatile("s_waitcnt vmcnt(2) lgkmcnt(0)" ::: "memory");          \
        __builtin_amdgcn_s_barrier();                                        \
        __builtin_amdgcn_sched_barrier(0);                                   \
    }                                                                        \
} while (0)

    // ---------------- main loop: bodies 0..59, counted barriers ----------
    for (int t = 0; t < 60; t += 2) {
        BODY(t,     A0, B0, A1, B1, rA0, true, true, false);
        BODY(t + 1, A1, B1, A0, B0, rA1, true, true, false);
    }
    // ---------------- tail: bodies 60..63, full barriers ------------------
    BODY(60, A0, B0, A1, B1, rA0, true,  true,  true);   // reload rA0<-data63
    BODY(61, A1, B1, A0, B0, rA1, true,  false, true);
    BODY(62, A0, B0, A1, B1, rA0, true,  false, true);
    BODY(63, A1, B1, A0, B0, rA1, false, false, true);
#undef BODY

    // ---------------- epilogue: relu(acc + hb) * w_att, col-reduce --------
    float* red = (float*)smem;   // [2][64]
    const int l4 = lane >> 4;

    float w4[4];
#pragma unroll
    for (int fn = 0; fn < 4; ++fn) w4[fn] = w_att[a0 + wn * 64 + fn * 16 + fl];

#pragma unroll
    for (int fm = 0; fm < 2; ++fm) {
#pragma unroll
        for (int rg = 0; rg < 4; ++rg) {
            int row = wm * 32 + fm * 16 + l4 * 4 + rg;
            int grow = r0 + row;
            int bb = grow / 196;
            const float* hbrow = hb + bb * 512 + a0 + wn * 64;
            float s = 0.f;
#pragma unroll
            for (int fn = 0; fn < 4; ++fn) {
                float v = acc[fm][fn][rg] + hbrow[fn * 16 + fl];
                v = fmaxf(v, 0.f);
                s = fmaf(v, w4[fn], s);
            }
#pragma unroll
            for (int m = 1; m < 16; m <<= 1) s += __shfl_xor(s, m, 64);
            if (fl == 0) red[wn * 64 + row] = s;
        }
    }
    __syncthreads();
    if (tid < 64) {
        partials[cb * 25088 + r0 + tid] = red[tid] + red[64 + tid];
    }
}

// ---------------------------------------------------------------------------
// Kernel 4: softmax over N=196 per batch.
// ---------------------------------------------------------------------------
__global__ __launch_bounds__(256) void softmax_k(
    const float* __restrict__ partials, const float* __restrict__ betap,
    const float* __restrict__ b_att,
    float* __restrict__ out_w, float* __restrict__ wbeta)
{
    const int b = blockIdx.x;
    const int t = threadIdx.x;
    const int lane = t & 63, wid = t >> 6;
    __shared__ float red[4];

    float scv = 0.f, sc = -1e30f;
    if (t < 196) {
        int r = b * 196 + t;
        scv = partials[r] + partials[25088 + r] + partials[2 * 25088 + r] +
              partials[3 * 25088 + r] + b_att[0];
        sc = scv;
    }
    float m = sc;
#pragma unroll
    for (int k = 32; k >= 1; k >>= 1) m = fmaxf(m, __shfl_xor(m, k, 64));
    if (lane == 0) red[wid] = m;
    __syncthreads();
    m = fmaxf(fmaxf(red[0], red[1]), fmaxf(red[2], red[3]));

    float e = (t < 196) ? __expf(scv - m) : 0.f;
    float ssum = e;
#pragma unroll
    for (int k = 32; k >= 1; k >>= 1) ssum += __shfl_xor(ssum, k, 64);
    __syncthreads();
    if (lane == 0) red[wid] = ssum;
    __syncthreads();
    float denom = red[0] + red[1] + red[2] + red[3];

    if (t < 196) {
        float w = e / denom;
        out_w[b * 196 + t] = w;
        wbeta[b * 196 + t] = w * betap[b];
    }
}

// ---------------------------------------------------------------------------
// Kernel 5: context[b][c] = sum_n wbeta[b][n] * img[b][n][c]
// ---------------------------------------------------------------------------
__global__ __launch_bounds__(256) void ctx_k(
    const float* __restrict__ img, const float* __restrict__ wbeta,
    float* __restrict__ out)
{
    const int b = blockIdx.y;
    const int c0 = blockIdx.x * 512 + threadIdx.x * 2;
    __shared__ float w[200];
    if (threadIdx.x < 196) w[threadIdx.x] = wbeta[b * 196 + threadIdx.x];
    __syncthreads();
    const float* base = img + (size_t)b * 196 * 2048 + c0;
    float acx = 0.f, acy = 0.f;
#pragma unroll 4
    for (int n = 0; n < 196; ++n) {
        float2 v = *(const float2*)(base + (size_t)n * 2048);
        float wn = w[n];
        acx = fmaf(wn, v.x, acx);
        acy = fmaf(wn, v.y, acy);
    }
    float2 r; r.x = acx; r.y = acy;
    *(float2*)(out + b * 2048 + c0) = r;
}

// ---------------------------------------------------------------------------
extern "C" void kernel_launch(void* const* d_in, const int* in_sizes, int n_in,
                              void* d_out, int out_size, void* d_ws, size_t ws_size,
                              hipStream_t stream)
{
    const float* img    = (const float*)d_in[0];
    const float* hidden = (const float*)d_in[1];
    const float* W_img  = (const float*)d_in[2];
    const float* b_img  = (const float*)d_in[3];
    const float* W_hid  = (const float*)d_in[4];
    const float* b_hid  = (const float*)d_in[5];
    const float* w_att  = (const float*)d_in[6];
    const float* b_att  = (const float*)d_in[7];
    const float* w_beta = (const float*)d_in[8];
    const float* b_beta = (const float*)d_in[9];

    char* ws = (char*)d_ws;
    unsigned short* Wt = (unsigned short*)ws;            // [512][2048] bf16: 2 MB
    float* hbp   = (float*)(ws + 2097152);               // [128][512]
    float* betap = (float*)(ws + 2359296);               // [128]
    float* parts = (float*)(ws + 2359808);               // [4][25088]
    float* wbeta = (float*)(ws + 2761216);               // [128][196]

    float* out_ctx = (float*)d_out;                      // [128][2048]
    float* out_w   = out_ctx + 128 * 2048;               // [128][196]

    wt_k<<<dim3(32, 8), 256, 0, stream>>>(W_img, Wt);
    hid_k<<<128, 256, 0, stream>>>(hidden, W_hid, b_hid, b_img, w_beta, b_beta,
                                   hbp, betap);
    scores_gemm<<<1568, 256, 0, stream>>>(img, Wt, hbp, w_att, parts);
    softmax_k<<<128, 256, 0, stream>>>(parts, betap, b_att, out_w, wbeta);
    ctx_k<<<dim3(4, 128), 256, 0, stream>>>(img, wbeta, out_ctx);
}